// Round 3
// baseline (18.149 us; speedup 1.0000x reference)
//
#include <hip/hip_runtime.h>
#include <hip/hip_bf16.h>

// Problem constants (from reference setup_inputs)
#define XW   65536   // W
#define XC   256     // C
#define XL   512     // LATENT_DIM (output bins)
#define BIN  128     // W / L elements per bin

// One block per PAIR of bins (256 w's = 1 KB contiguous per channel).
// 1024 threads = 16 channel-groups x 64 lanes (float4 => 4 w's/lane).
// Each 64-lane wave reads 1 KB contiguous per channel-step (vs 512 B before)
// => better HBM row-buffer locality. 16 channel-steps, c = step*16 + cg.
// Only batch 0 of x is read (output depends only on batch 0).
__global__ __launch_bounds__(1024) void statspool_kernel(
    const float* __restrict__ x,     // [B,C,1,W] -- we read only b=0
    const float* __restrict__ cw,    // [1,C]
    const float* __restrict__ cb,    // [1]
    const float* __restrict__ eps,   // [L]
    float* __restrict__ out)         // [1,L]
{
    const int bp = blockIdx.x;       // bin pair 0..255
    const int t  = threadIdx.x;      // 0..1023
    const int wi = t & 63;           // lane -> w = wi*4 .. wi*4+3 (0..255)
    const int cg = t >> 6;           // channel subgroup 0..15 (wave-uniform)

    const float* xp = x + (size_t)cg * XW + bp * 256 + (wi << 2);

    float4 acc = make_float4(0.f, 0.f, 0.f, 0.f);
    #pragma unroll
    for (int s = 0; s < 16; ++s) {
        const float wc = cw[s * 16 + cg];                  // wave-uniform -> s_load
        const float4 v = *(const float4*)(xp + (size_t)s * 16 * XW);
        acc.x = fmaf(wc, v.x, acc.x);
        acc.y = fmaf(wc, v.y, acc.y);
        acc.z = fmaf(wc, v.z, acc.z);
        acc.w = fmaf(wc, v.w, acc.w);
    }

    // Stage partials: part[cg][w], contiguous b128 writes, stride-1 reads.
    __shared__ float part[16 * 256];   // 16 KB
    __shared__ float ob[256];          // o values for the 2 bins
    *(float4*)(part + (cg << 8) + (wi << 2)) = acc;
    __syncthreads();

    // 256 threads each own one w: sum 16 channel-group partials + bias.
    if (t < 256) {
        float s = 0.f;
        #pragma unroll
        for (int g = 0; g < 16; ++g) s += part[(g << 8) + t];
        ob[t] = s + cb[0];
    }
    __syncthreads();

    // Two waves, one bin each: reduce sum / sum-of-squares over 128 o's.
    if (t < 128) {
        const int bin = t >> 6;        // wave 0 -> bin 0, wave 1 -> bin 1
        const int ln  = t & 63;
        const float o0 = ob[bin * BIN + ln];
        const float o1 = ob[bin * BIN + ln + 64];
        float s  = o0 + o1;
        float sq = fmaf(o0, o0, o1 * o1);
        #pragma unroll
        for (int off = 32; off; off >>= 1) {
            s  += __shfl_down(s,  off);
            sq += __shfl_down(sq, off);
        }
        if (ln == 0) {
            const float inv  = 1.0f / (float)BIN;
            const float mean = s * inv;
            const float msq  = sq * inv;
            const float var  = fmaxf(msq - mean * mean, 0.0f);
            const int l = bp * 2 + bin;
            out[l] = fmaf(sqrtf(var), eps[l], mean);
        }
    }
}

extern "C" void kernel_launch(void* const* d_in, const int* in_sizes, int n_in,
                              void* d_out, int out_size, void* d_ws, size_t ws_size,
                              hipStream_t stream) {
    const float* x   = (const float*)d_in[0];   // [8,256,1,65536] f32
    const float* cw  = (const float*)d_in[1];   // [1,256] f32
    const float* cb  = (const float*)d_in[2];   // [1] f32
    const float* eps = (const float*)d_in[3];   // [512] f32
    float* out = (float*)d_out;                 // [1,512] f32

    statspool_kernel<<<dim3(XL / 2), dim3(1024), 0, stream>>>(x, cw, cb, eps, out);
}